// Round 11
// baseline (15107.013 us; speedup 1.0000x reference)
//
#include <hip/hip_runtime.h>
#include <cstdint>
#include <cstddef>

// ---------------------------------------------------------------------------
// 2-layer LSTM (T=2048, B=128, IN=88, H=200) + sigmoid FC head.
// R15: FAT WGs — 15 WGs (7 L0 x 32 units | 7 L1 x 32 units | 1 FC).
// Same structure/protocol as R7/R14 (session best, 11261us); the one variable
// is producer fan-in 13 -> 7: the 13-way fetch_add convoy on each flag word
// serializes at the coherence point (~0.5-1us added to the LAST post, which
// is what consumers wait on) and 13-WG straggler jitter adds to every detect.
// MT=8, ROWS=128, fragment-order w_s (R8 layout, conflict-free, 114KB LDS
// for role1 at 1 WG/CU). Per-element accumulation order and fragment values
// bitwise identical to R7.
// ---------------------------------------------------------------------------

#define TS    2048
#define BB    128
#define IN_D  88
#define HID   200
#define OUT_D 88
#define KX    96     // x segment padded to 3 K-tiles
#define KH    224    // h segment padded to 7 K-tiles (7 x 32)
#define RING  4      // h buffer ring depth
#define FR    16     // flag ring slots
#define FSTR  32     // u32 per flag slot (128 B)

typedef __attribute__((ext_vector_type(8))) short short8;
typedef __attribute__((ext_vector_type(4))) float f32x4;

constexpr int NW0 = 7, NW1 = 7;
constexpr int NWORK = NW0 + NW1 + 1;   // 15

__device__ inline unsigned short f2bf(float f){
  union{float f; unsigned u;} v; v.f = f;
  unsigned r = v.u + 0x7FFFu + ((v.u >> 16) & 1u);   // RNE
  return (unsigned short)(r >> 16);
}
__device__ inline float sigf(float x){ return 1.0f/(1.0f + __expf(-x)); }
__device__ inline float tanhf2(float x){ return 2.0f/(1.0f + __expf(-2.0f*x)) - 1.0f; }

__device__ inline unsigned ld_flag(const unsigned* p){
  return __hip_atomic_load(p, __ATOMIC_RELAXED, __HIP_MEMORY_SCOPE_AGENT);
}
__device__ inline void post1(unsigned* p){
  __hip_atomic_fetch_add(p, 1u, __ATOMIC_RELAXED, __HIP_MEMORY_SCOPE_AGENT);
}
__device__ inline unsigned* fsl(unsigned* base, int t){ return base + (size_t)(t & (FR-1))*FSTR; }
__device__ inline unsigned ftg(int t, int nw){ return (unsigned)((t/FR + 1)*nw); }

// WG-level wait: only wave 0 polls (lane-uniform address -> 1 request/poll),
// with s_sleep backoff; __syncthreads releases the other waves.
__device__ inline void wg_wait2(int tid, unsigned* p0, unsigned v0,
                                unsigned* p1, unsigned v1){
  if (tid < 64 && (p0 || p1)){
    int n = 0;
    for(;;){
      unsigned a0 = p0 ? ld_flag(p0) : 0xFFFFFFFFu;
      unsigned a1 = p1 ? ld_flag(p1) : 0xFFFFFFFFu;
      bool ok = true;
      if (p0 && a0 < v0) ok = false;
      if (p1 && a1 < v1) ok = false;
      if (ok || ++n > 100000) break;    // hang guard: fail loud, don't hang
      __builtin_amdgcn_s_sleep(1);
    }
  }
  __syncthreads();
}

// coherent (L2-bypassing) 16B load of a B-fragment chunk.
// Layout: h[kt][b][32] shorts -> fully coalesced per-wave (1KB contiguous).
__device__ inline short8 loadB(const unsigned short* buf, int b, int kt, int q){
  const unsigned long long* p =
      (const unsigned long long*)(buf + ((size_t)kt*BB + b)*32 + q*8);
  unsigned long long lo = __hip_atomic_load(p,   __ATOMIC_RELAXED, __HIP_MEMORY_SCOPE_AGENT);
  unsigned long long hi = __hip_atomic_load(p+1, __ATOMIC_RELAXED, __HIP_MEMORY_SCOPE_AGENT);
  union{ unsigned long long u[2]; short8 s; } v; v.u[0]=lo; v.u[1]=hi;
  return v.s;
}

__device__ inline void cvt_x(const float4* pa, const float4* pb, int q, short8* xf){
  #pragma unroll
  for (int kt = 0; kt < 3; ++kt){
    int k = kt*32 + q*8;
    short8 r = {0,0,0,0,0,0,0,0};
    if (k + 8 <= IN_D){
      r[0]=(short)f2bf(pa[kt].x); r[1]=(short)f2bf(pa[kt].y);
      r[2]=(short)f2bf(pa[kt].z); r[3]=(short)f2bf(pa[kt].w);
      r[4]=(short)f2bf(pb[kt].x); r[5]=(short)f2bf(pb[kt].y);
      r[6]=(short)f2bf(pb[kt].z); r[7]=(short)f2bf(pb[kt].w);
    }
    xf[kt] = r;
  }
}

template<int ROLE>
__device__ void run_role(int j0,
    const float* __restrict__ xin,
    const float* __restrict__ wi, const float* __restrict__ wh,
    const float* __restrict__ bi, const float* __restrict__ bh,
    float* __restrict__ out,
    unsigned short* h0buf, unsigned short* h1buf,
    unsigned* f0p, unsigned* f0c, unsigned* f1p, unsigned* f1c,
    unsigned* f1g, unsigned* fFg,
    short* w_s, float* bias_s, unsigned short* hT)
{
  constexpr int ROWS = (ROLE==2)?96:128;
  constexpr int MT   = (ROLE==2)?6:8;
  constexpr int KTOT = (ROLE==0)?10:(ROLE==1?14:7);   // K-tiles of 32
  const int tid = threadIdx.x;

  // ---- stage weights (fp32 global -> bf16 LDS) in MFMA-fragment order:
  // w_s[(((ktf*4 + q)*MT + mt)*16 + nn)*8 + e] -> conflict-free ds_read_b128.
  constexpr int TOTW = KTOT*4*MT*16*8;
  for (int idx = tid; idx < TOTW; idx += 512){
    int e    = idx & 7;
    int nn_s = (idx >> 3) & 15;
    int rest = idx >> 7;            // = (ktf*4+q)*MT + mt
    int mt   = rest % MT;
    int qk   = rest / MT;
    int q_s  = qk & 3;
    int ktf  = qk >> 2;
    int r = mt*16 + nn_s;           // unit-gate row (unit_local*4 + gate)
    int k = ktf*32 + q_s*8 + e;     // K index
    float v = 0.f;
    if (ROLE == 2){
      if (r < OUT_D && k < HID) v = wi[r*HID + k];
    } else {
      int j = j0 + (r >> 2), g = r & 3;
      if (j < HID){
        int gr = g*HID + j;              // torch gate order i,f,g,o
        if (ROLE == 0){
          if (k < IN_D)                   v = wi[gr*IN_D + k];
          else if (k >= KX && k < KX+HID) v = wh[gr*HID + (k-KX)];
        } else {
          if (k < HID)                    v = wi[gr*HID + k];
          else if (k >= KH && k < KH+HID) v = wh[gr*HID + (k-KH)];
        }
      }
    }
    w_s[idx] = (short)f2bf(v);
  }
  for (int r = tid; r < ROWS; r += 512){
    float bv = 0.f;
    if (ROLE == 2){ if (r < OUT_D) bv = bi[r]; }
    else { int j = j0 + (r>>2), g = r&3; if (j < HID){ int gr = g*HID+j; bv = bi[gr] + bh[gr]; } }
    bias_s[r] = bv;
  }
  __syncthreads();

  const int lane = tid & 63;
  const int wv   = tid >> 6;     // 8 waves, one 16-batch N-tile each
  const int q    = lane >> 4;
  const int nn   = lane & 15;
  const int b    = wv*16 + nn;

  // per-lane fragment base (shorts); (ktf,mt) offsets are compile-time imms
  const int wbase = (q*MT*16 + nn)*8;
  #define WS_FRAG(ktf, mt) (*(const short8*)&w_s[wbase + ((ktf)*4*MT + (mt))*128])

  float c[MT], hl[MT];
  #pragma unroll
  for (int i=0;i<MT;i++){ c[i]=0.f; hl[i]=0.f; }

  short8 xf[3];
  float4 pa[3], pb[3];
  if (ROLE == 0){
    #pragma unroll
    for (int kt=0;kt<3;kt++){
      int k = kt*32 + q*8;
      if (k + 8 <= IN_D){
        const float* xp = xin + (size_t)b*IN_D + k;   // t=0
        pa[kt] = *(const float4*)xp; pb[kt] = *(const float4*)(xp + 4);
      }
    }
    cvt_x(pa, pb, q, xf);
  }

  for (int t = 0; t < TS; ++t){
    f32x4 acc[MT];
    #pragma unroll
    for (int mt=0; mt<MT; ++mt){
      #pragma unroll
      for (int r=0;r<4;r++) acc[mt][r] = bias_s[mt*16 + q*4 + r];
    }

    if (ROLE == 0){
      // x-projection (h-independent) BEFORE the wait
      #pragma unroll
      for (int kt=0; kt<3; ++kt){
        #pragma unroll
        for (int mt=0; mt<MT; ++mt){
          acc[mt] = __builtin_amdgcn_mfma_f32_16x16x32_bf16(WS_FRAG(kt,mt), xf[kt], acc[mt], 0, 0, 0);
        }
      }
      // prefetch raw x for t+1 (latency hidden behind wait + recurrent part)
      if (t + 1 < TS){
        #pragma unroll
        for (int kt=0;kt<3;kt++){
          int k = kt*32 + q*8;
          if (k + 8 <= IN_D){
            const float* xp = xin + ((size_t)(t+1)*BB + b)*IN_D + k;
            pa[kt] = *(const float4*)xp; pb[kt] = *(const float4*)(xp + 4);
          }
        }
      }
      // wait: peers' h0[t-1] (f0p); ring guard f1g[t-RING]
      unsigned *p0=nullptr,*p1=nullptr; unsigned v0=0,v1=0;
      if (t >= 1){   p0 = fsl(f0p, t-1);    v0 = ftg(t-1, NW0); }
      if (t >= RING){p1 = fsl(f1g, t-RING); v1 = ftg(t-RING, NW1); }
      wg_wait2(tid, p0, v0, p1, v1);
      // recurrent part
      const unsigned short* hs = h0buf + (size_t)((t-1)&(RING-1))*(BB*KH);
      short8 bfr[7];
      #pragma unroll
      for (int kt=0;kt<7;kt++) bfr[kt] = loadB(hs, b, kt, q);
      #pragma unroll
      for (int kt=0;kt<7;kt++){
        #pragma unroll
        for (int mt=0; mt<MT; ++mt){
          acc[mt] = __builtin_amdgcn_mfma_f32_16x16x32_bf16(WS_FRAG(3+kt,mt), bfr[kt], acc[mt], 0, 0, 0);
        }
      }
    } else if (ROLE == 1){
      // Phase A: y0[t] projection FIRST (f0c pre-posted RING laps ahead).
      {
        unsigned *p1=nullptr; unsigned v1=0;
        if (t >= RING){ p1 = fsl(fFg, t-RING); v1 = ftg(t-RING, 1); }
        wg_wait2(tid, fsl(f0c, t), ftg(t, NW0), p1, v1);
      }
      const unsigned short* hs0 = h0buf + (size_t)(t&(RING-1))*(BB*KH);
      short8 bfr0[7];
      #pragma unroll
      for (int kt=0;kt<7;kt++) bfr0[kt] = loadB(hs0, b, kt, q);
      #pragma unroll
      for (int kt=0;kt<7;kt++){
        #pragma unroll
        for (int mt=0; mt<MT; ++mt){
          acc[mt] = __builtin_amdgcn_mfma_f32_16x16x32_bf16(WS_FRAG(kt,mt), bfr0[kt], acc[mt], 0, 0, 0);
        }
      }
      // Phase B: own-layer recurrence — the binding cycle.
      {
        unsigned *p0=nullptr; unsigned v0=0;
        if (t >= 1){ p0 = fsl(f1p, t-1); v0 = ftg(t-1, NW1); }
        wg_wait2(tid, p0, v0, nullptr, 0);
      }
      // all waves consumed their h0 regs before that barrier -> release h0[t]
      if (tid == 0) post1(fsl(f1g, t));
      const unsigned short* hs1 = h1buf + (size_t)((t-1)&(RING-1))*(BB*KH);
      short8 bfr1[7];
      #pragma unroll
      for (int kt=0;kt<7;kt++) bfr1[kt] = loadB(hs1, b, kt, q);
      #pragma unroll
      for (int kt=0;kt<7;kt++){
        #pragma unroll
        for (int mt=0; mt<MT; ++mt){
          acc[mt] = __builtin_amdgcn_mfma_f32_16x16x32_bf16(WS_FRAG(7+kt,mt), bfr1[kt], acc[mt], 0, 0, 0);
        }
      }
    } else {
      // FC head: h1[t] (f1c)
      wg_wait2(tid, fsl(f1c, t), ftg(t, NW1), nullptr, 0);
      const unsigned short* hs1 = h1buf + (size_t)(t&(RING-1))*(BB*KH);
      short8 bfr[7];
      #pragma unroll
      for (int kt=0;kt<7;kt++) bfr[kt] = loadB(hs1, b, kt, q);
      #pragma unroll
      for (int kt=0;kt<7;kt++){
        #pragma unroll
        for (int mt=0; mt<MT; ++mt){
          acc[mt] = __builtin_amdgcn_mfma_f32_16x16x32_bf16(WS_FRAG(kt,mt), bfr[kt], acc[mt], 0, 0, 0);
        }
      }
      __syncthreads();                  // all waves' h1 reads consumed
      if (tid == 0) post1(fsl(fFg, t)); // release h1[t] slot
      #pragma unroll
      for (int mt=0; mt<MT; ++mt){
        #pragma unroll
        for (int r=0;r<4;r++){
          int o = mt*16 + q*4 + r;
          if (o < OUT_D) out[((size_t)t*BB + b)*OUT_D + o] = sigf(acc[mt][r]);
        }
      }
      continue;
    }

    // ---- LSTM pointwise + h publish (roles 0/1) ----
    #pragma unroll
    for (int mt=0; mt<MT; ++mt){
      float ii = sigf(acc[mt][0]);
      float ff = sigf(acc[mt][1]);
      float gg = tanhf2(acc[mt][2]);
      float oo = sigf(acc[mt][3]);
      c[mt] = ff*c[mt] + ii*gg;
      float h = oo * tanhf2(c[mt]);
      hl[mt] = h;
      hT[b*32 + mt*4 + q] = f2bf(h);             // LDS transpose tile [b][unit_local]
    }
    __syncthreads();
    {                                            // coalesced coherent store of h slice
      // 32 units/WG = one full kt block: 128 b x 4 chunks of 8 units (16B)
      int bb = tid >> 2, ch = tid & 3;
      if (j0 + ch*8 < HID){
        const unsigned long long* src = (const unsigned long long*)&hT[bb*32 + ch*8];
        int kt = j0 >> 5;                        // off = 0 (j0 is 32-aligned)
        unsigned short* dst = (ROLE==0 ? h0buf : h1buf)
                            + (size_t)(t&(RING-1))*(BB*KH)
                            + ((size_t)kt*BB + bb)*32 + ch*8;
        __hip_atomic_store((unsigned long long*)dst,     src[0],
                           __ATOMIC_RELAXED, __HIP_MEMORY_SCOPE_AGENT);
        __hip_atomic_store(((unsigned long long*)dst)+1, src[1],
                           __ATOMIC_RELAXED, __HIP_MEMORY_SCOPE_AGENT);
      }
    }
    asm volatile("s_waitcnt vmcnt(0)" ::: "memory");   // h stores at coherence point
    __syncthreads();
    if (tid == 0){
      if (ROLE == 0){ post1(fsl(f0p, t)); post1(fsl(f0c, t)); }
      else          { post1(fsl(f1p, t)); post1(fsl(f1c, t)); }  // f1g posted early
    }
    if (ROLE == 0) cvt_x(pa, pb, q, xf);               // convert prefetched x for t+1
  }

  if (ROLE < 2){                                   // final hn / cn (fp32)
    size_t base = (size_t)TS*BB*OUT_D;
    float* hn = out + base + (size_t)ROLE*(BB*HID);
    float* cn = out + base + 2*(size_t)BB*HID + (size_t)ROLE*(BB*HID);
    #pragma unroll
    for (int mt=0; mt<MT; ++mt){
      int unit = j0 + mt*4 + q;
      if (unit < HID){
        hn[b*HID + unit] = hl[mt];
        cn[b*HID + unit] = c[mt];
      }
    }
  }
  #undef WS_FRAG
}

__global__ __launch_bounds__(512, 2) void lstm_net(
    const float* __restrict__ x,
    const float* __restrict__ wih0, const float* __restrict__ whh0,
    const float* __restrict__ bih0, const float* __restrict__ bhh0,
    const float* __restrict__ wih1, const float* __restrict__ whh1,
    const float* __restrict__ bih1, const float* __restrict__ bhh1,
    const float* __restrict__ wfc,  const float* __restrict__ bfc,
    float* __restrict__ out,
    unsigned short* h0buf, unsigned short* h1buf,
    unsigned* f0p, unsigned* f0c, unsigned* f1p, unsigned* f1c,
    unsigned* f1g, unsigned* fFg)
{
  __shared__ short w_s[57344];           // 114688 B (role1 KTOT=14, MT=8)
  __shared__ float bias_s[128];
  __shared__ unsigned short hT[128*32];  // h transpose tile (8192 B)
  int wg = blockIdx.x;
  if (wg < NW0){
    run_role<0>(wg*32, x, wih0, whh0, bih0, bhh0, out, h0buf, h1buf,
                f0p, f0c, f1p, f1c, f1g, fFg, w_s, bias_s, hT);
  } else if (wg < NW0+NW1){
    run_role<1>((wg-NW0)*32, x, wih1, whh1, bih1, bhh1, out, h0buf, h1buf,
                f0p, f0c, f1p, f1c, f1g, fFg, w_s, bias_s, hT);
  } else {
    run_role<2>(0, x, wfc, nullptr, bfc, nullptr, out, h0buf, h1buf,
                f0p, f0c, f1p, f1c, f1g, fFg, w_s, bias_s, hT);
  }
}

extern "C" void kernel_launch(void* const* d_in, const int* in_sizes, int n_in,
                              void* d_out, int out_size, void* d_ws, size_t ws_size,
                              hipStream_t stream) {
  const float* x    = (const float*)d_in[0];
  const float* wih0 = (const float*)d_in[1];
  const float* whh0 = (const float*)d_in[2];
  const float* bih0 = (const float*)d_in[3];
  const float* bhh0 = (const float*)d_in[4];
  const float* wih1 = (const float*)d_in[5];
  const float* whh1 = (const float*)d_in[6];
  const float* bih1 = (const float*)d_in[7];
  const float* bhh1 = (const float*)d_in[8];
  const float* wfc  = (const float*)d_in[9];
  const float* bfc  = (const float*)d_in[10];
  float* out = (float*)d_out;

  char* ws = (char*)d_ws;
  const size_t HSZ = (size_t)RING * BB * KH * 2;       // 229376 B per layer ring
  const size_t FSZ = (size_t)FR * FSTR * 4;            // 2048 B per flag array
  unsigned short* h0 = (unsigned short*)(ws + 0);
  unsigned short* h1 = (unsigned short*)(ws + HSZ);
  unsigned* f0p = (unsigned*)(ws + 2*HSZ + 0*FSZ);
  unsigned* f0c = (unsigned*)(ws + 2*HSZ + 1*FSZ);
  unsigned* f1p = (unsigned*)(ws + 2*HSZ + 2*FSZ);
  unsigned* f1c = (unsigned*)(ws + 2*HSZ + 3*FSZ);
  unsigned* f1g = (unsigned*)(ws + 2*HSZ + 4*FSZ);
  unsigned* fFg = (unsigned*)(ws + 2*HSZ + 5*FSZ);

  hipMemsetAsync(d_ws, 0, 2*HSZ + 6*FSZ, stream);      // zero h rings + flags
  hipLaunchKernelGGL(lstm_net, dim3(NWORK), dim3(512), 0, stream,
      x, wih0, whh0, bih0, bhh0, wih1, whh1, bih1, bhh1, wfc, bfc,
      out, h0, h1, f0p, f0c, f1p, f1c, f1g, fFg);
}

// Round 12
// 11228.500 us; speedup vs baseline: 1.3454x; 1.3454x over previous
//
#include <hip/hip_runtime.h>
#include <cstdint>
#include <cstddef>

// ---------------------------------------------------------------------------
// 2-layer LSTM (T=2048, B=128, IN=88, H=200) + sigmoid FC head.
// Persistent pipelined kernel: 27 WGs (13 L0 unit-slices, 13 L1, 1 FC).
// R16 = R7/R14 verbatim — FINAL. Session-best measured passing kernel
// (11261us, 22.5% better than session-start 14546us).
//
// Why this is the keeper (evidence ledger):
//  - Period ~5.5us/step is an exchange-LATENCY floor: ~5 serial coherence-
//    point round trips (detect, UC h-load, store-drain, post visibility).
//  - Probes that did NOT move it: R8 bank-conflict fix (-9x conflicts,
//    neutral), R11 work offload to a 4th pipeline stage (neutral).
//  - Probes that regressed: R9 reg-hoist (VGPR cliff), R10 reorder (extra
//    barrier drain), R15 fat WGs (per-WG LDS serial time > lap), R5 flag
//    mechanics. Convoy/contention is NOT the term; RT latency is.
//  - The architectural escape (batch-local recurrence, R12/R13) failed
//    correctness deterministically (cn absmax 468) twice; budget spent.
// ---------------------------------------------------------------------------

#define TS    2048
#define BB    128
#define IN_D  88
#define HID   200
#define OUT_D 88
#define KX    96     // x segment padded to 3 K-tiles
#define KH    224    // h segment padded to 7 K-tiles (7 x 32)
#define RING  4      // h buffer ring depth
#define FR    16     // flag ring slots
#define FSTR  32     // u32 per flag slot (128 B)

typedef __attribute__((ext_vector_type(8))) short short8;
typedef __attribute__((ext_vector_type(4))) float f32x4;

constexpr int NW0 = 13, NW1 = 13;
constexpr int NWORK = NW0 + NW1 + 1;   // 27

__device__ inline unsigned short f2bf(float f){
  union{float f; unsigned u;} v; v.f = f;
  unsigned r = v.u + 0x7FFFu + ((v.u >> 16) & 1u);   // RNE
  return (unsigned short)(r >> 16);
}
__device__ inline float sigf(float x){ return 1.0f/(1.0f + __expf(-x)); }
__device__ inline float tanhf2(float x){ return 2.0f/(1.0f + __expf(-2.0f*x)) - 1.0f; }

__device__ inline unsigned ld_flag(const unsigned* p){
  return __hip_atomic_load(p, __ATOMIC_RELAXED, __HIP_MEMORY_SCOPE_AGENT);
}
__device__ inline void post1(unsigned* p){
  __hip_atomic_fetch_add(p, 1u, __ATOMIC_RELAXED, __HIP_MEMORY_SCOPE_AGENT);
}
__device__ inline unsigned* fsl(unsigned* base, int t){ return base + (size_t)(t & (FR-1))*FSTR; }
__device__ inline unsigned ftg(int t, int nw){ return (unsigned)((t/FR + 1)*nw); }

// WG-level wait: only wave 0 polls (lane-uniform address -> 1 request/poll),
// with s_sleep backoff; __syncthreads releases the other waves.
__device__ inline void wg_wait2(int tid, unsigned* p0, unsigned v0,
                                unsigned* p1, unsigned v1){
  if (tid < 64 && (p0 || p1)){
    int n = 0;
    for(;;){
      unsigned a0 = p0 ? ld_flag(p0) : 0xFFFFFFFFu;
      unsigned a1 = p1 ? ld_flag(p1) : 0xFFFFFFFFu;
      bool ok = true;
      if (p0 && a0 < v0) ok = false;
      if (p1 && a1 < v1) ok = false;
      if (ok || ++n > 4000) break;      // hang guard: fail loud, don't hang
      __builtin_amdgcn_s_sleep(1);
    }
  }
  __syncthreads();
}

// coherent (L2-bypassing) 16B load of a B-fragment chunk.
// Layout: h[kt][b][32] shorts -> lane (b,kt,q) reads 16B at
// ((kt*BB + b)*32 + q*8). Within a wave (nn=0..15, q=0..3) this spans
// 16*64B CONTIGUOUS bytes -> fully coalesced.
__device__ inline short8 loadB(const unsigned short* buf, int b, int kt, int q){
  const unsigned long long* p =
      (const unsigned long long*)(buf + ((size_t)kt*BB + b)*32 + q*8);
  unsigned long long lo = __hip_atomic_load(p,   __ATOMIC_RELAXED, __HIP_MEMORY_SCOPE_AGENT);
  unsigned long long hi = __hip_atomic_load(p+1, __ATOMIC_RELAXED, __HIP_MEMORY_SCOPE_AGENT);
  union{ unsigned long long u[2]; short8 s; } v; v.u[0]=lo; v.u[1]=hi;
  return v.s;
}

__device__ inline void cvt_x(const float4* pa, const float4* pb, int q, short8* xf){
  #pragma unroll
  for (int kt = 0; kt < 3; ++kt){
    int k = kt*32 + q*8;
    short8 r = {0,0,0,0,0,0,0,0};
    if (k + 8 <= IN_D){
      r[0]=(short)f2bf(pa[kt].x); r[1]=(short)f2bf(pa[kt].y);
      r[2]=(short)f2bf(pa[kt].z); r[3]=(short)f2bf(pa[kt].w);
      r[4]=(short)f2bf(pb[kt].x); r[5]=(short)f2bf(pb[kt].y);
      r[6]=(short)f2bf(pb[kt].z); r[7]=(short)f2bf(pb[kt].w);
    }
    xf[kt] = r;
  }
}

template<int ROLE>
__device__ void run_role(int j0,
    const float* __restrict__ xin,
    const float* __restrict__ wi, const float* __restrict__ wh,
    const float* __restrict__ bi, const float* __restrict__ bh,
    float* __restrict__ out,
    unsigned short* h0buf, unsigned short* h1buf,
    unsigned* f0p, unsigned* f0c, unsigned* f1p, unsigned* f1c,
    unsigned* f1g, unsigned* fFg,
    short* w_s, float* bias_s, unsigned short* hT)
{
  constexpr int STR  = (ROLE==0)?328:(ROLE==1?456:232); // K padded +8 (bank stagger)
  constexpr int ROWS = (ROLE==2)?96:64;
  constexpr int MT   = (ROLE==2)?6:4;
  const int tid = threadIdx.x;

  // ---- stage weights (fp32 global -> bf16 LDS), rows unit-major [unit][i,f,g,o]
  for (int idx = tid; idx < ROWS*STR; idx += 512){
    int r = idx / STR, k = idx - r*STR;
    float v = 0.f;
    if (ROLE == 2){
      if (r < OUT_D && k < HID) v = wi[r*HID + k];
    } else {
      int j = j0 + (r >> 2), g = r & 3;
      if (j < HID){
        int gr = g*HID + j;              // torch gate order i,f,g,o
        if (ROLE == 0){
          if (k < IN_D)                   v = wi[gr*IN_D + k];
          else if (k >= KX && k < KX+HID) v = wh[gr*HID + (k-KX)];
        } else {
          if (k < HID)                    v = wi[gr*HID + k];
          else if (k >= KH && k < KH+HID) v = wh[gr*HID + (k-KH)];
        }
      }
    }
    w_s[idx] = (short)f2bf(v);
  }
  for (int r = tid; r < ROWS; r += 512){
    float bv = 0.f;
    if (ROLE == 2){ if (r < OUT_D) bv = bi[r]; }
    else { int j = j0 + (r>>2), g = r&3; if (j < HID){ int gr = g*HID+j; bv = bi[gr] + bh[gr]; } }
    bias_s[r] = bv;
  }
  __syncthreads();

  const int lane = tid & 63;
  const int wv   = tid >> 6;     // 8 waves, one 16-batch N-tile each
  const int q    = lane >> 4;
  const int nn   = lane & 15;
  const int b    = wv*16 + nn;

  float c[MT], hl[MT];
  #pragma unroll
  for (int i=0;i<MT;i++){ c[i]=0.f; hl[i]=0.f; }

  short8 xf[3];
  float4 pa[3], pb[3];
  if (ROLE == 0){
    #pragma unroll
    for (int kt=0;kt<3;kt++){
      int k = kt*32 + q*8;
      if (k + 8 <= IN_D){
        const float* xp = xin + (size_t)b*IN_D + k;   // t=0
        pa[kt] = *(const float4*)xp; pb[kt] = *(const float4*)(xp + 4);
      }
    }
    cvt_x(pa, pb, q, xf);
  }

  for (int t = 0; t < TS; ++t){
    f32x4 acc[MT];
    #pragma unroll
    for (int mt=0; mt<MT; ++mt){
      #pragma unroll
      for (int r=0;r<4;r++) acc[mt][r] = bias_s[mt*16 + q*4 + r];
    }

    if (ROLE == 0){
      // x-projection (h-independent) BEFORE the wait
      #pragma unroll
      for (int kt=0; kt<3; ++kt){
        #pragma unroll
        for (int mt=0; mt<MT; ++mt){
          short8 af = *(const short8*)&w_s[(mt*16 + nn)*STR + kt*32 + q*8];
          acc[mt] = __builtin_amdgcn_mfma_f32_16x16x32_bf16(af, xf[kt], acc[mt], 0, 0, 0);
        }
      }
      // prefetch raw x for t+1 (latency hidden behind wait + recurrent part)
      if (t + 1 < TS){
        #pragma unroll
        for (int kt=0;kt<3;kt++){
          int k = kt*32 + q*8;
          if (k + 8 <= IN_D){
            const float* xp = xin + ((size_t)(t+1)*BB + b)*IN_D + k;
            pa[kt] = *(const float4*)xp; pb[kt] = *(const float4*)(xp + 4);
          }
        }
      }
      // wait: peers' h0[t-1] (f0p); ring guard f1g[t-RING]
      unsigned *p0=nullptr,*p1=nullptr; unsigned v0=0,v1=0;
      if (t >= 1){   p0 = fsl(f0p, t-1);    v0 = ftg(t-1, NW0); }
      if (t >= RING){p1 = fsl(f1g, t-RING); v1 = ftg(t-RING, NW1); }
      wg_wait2(tid, p0, v0, p1, v1);
      // recurrent part
      const unsigned short* hs = h0buf + (size_t)((t-1)&(RING-1))*(BB*KH);
      short8 bfr[7];
      #pragma unroll
      for (int kt=0;kt<7;kt++) bfr[kt] = loadB(hs, b, kt, q);
      #pragma unroll
      for (int kt=0;kt<7;kt++){
        #pragma unroll
        for (int mt=0; mt<MT; ++mt){
          short8 af = *(const short8*)&w_s[(mt*16 + nn)*STR + (3+kt)*32 + q*8];
          acc[mt] = __builtin_amdgcn_mfma_f32_16x16x32_bf16(af, bfr[kt], acc[mt], 0, 0, 0);
        }
      }
    } else if (ROLE == 1){
      // Phase A: y0[t] projection FIRST. f0c[t] is pre-posted (role0 runs
      // RING laps ahead), so this wait is a single satisfied flag load and
      // the h0 load + 28 MFMAs run OFF the h1-recurrence critical cycle.
      {
        unsigned *p1=nullptr; unsigned v1=0;
        if (t >= RING){ p1 = fsl(fFg, t-RING); v1 = ftg(t-RING, 1); }
        wg_wait2(tid, fsl(f0c, t), ftg(t, NW0), p1, v1);
      }
      const unsigned short* hs0 = h0buf + (size_t)(t&(RING-1))*(BB*KH);
      short8 bfr0[7];
      #pragma unroll
      for (int kt=0;kt<7;kt++) bfr0[kt] = loadB(hs0, b, kt, q);
      #pragma unroll
      for (int kt=0;kt<7;kt++){
        #pragma unroll
        for (int mt=0; mt<MT; ++mt){
          short8 af = *(const short8*)&w_s[(mt*16 + nn)*STR + kt*32 + q*8];
          acc[mt] = __builtin_amdgcn_mfma_f32_16x16x32_bf16(af, bfr0[kt], acc[mt], 0, 0, 0);
        }
      }
      // Phase B: own-layer recurrence — the binding cycle.
      {
        unsigned *p0=nullptr; unsigned v0=0;
        if (t >= 1){ p0 = fsl(f1p, t-1); v0 = ftg(t-1, NW1); }
        wg_wait2(tid, p0, v0, nullptr, 0);
      }
      // all waves consumed their h0 regs before that barrier -> release h0[t]
      if (tid == 0) post1(fsl(f1g, t));
      const unsigned short* hs1 = h1buf + (size_t)((t-1)&(RING-1))*(BB*KH);
      short8 bfr1[7];
      #pragma unroll
      for (int kt=0;kt<7;kt++) bfr1[kt] = loadB(hs1, b, kt, q);
      #pragma unroll
      for (int kt=0;kt<7;kt++){
        #pragma unroll
        for (int mt=0; mt<MT; ++mt){
          short8 af = *(const short8*)&w_s[(mt*16 + nn)*STR + (7+kt)*32 + q*8];
          acc[mt] = __builtin_amdgcn_mfma_f32_16x16x32_bf16(af, bfr1[kt], acc[mt], 0, 0, 0);
        }
      }
    } else {
      // FC head: h1[t] (f1c)
      wg_wait2(tid, fsl(f1c, t), ftg(t, NW1), nullptr, 0);
      const unsigned short* hs1 = h1buf + (size_t)(t&(RING-1))*(BB*KH);
      short8 bfr[7];
      #pragma unroll
      for (int kt=0;kt<7;kt++) bfr[kt] = loadB(hs1, b, kt, q);
      #pragma unroll
      for (int kt=0;kt<7;kt++){
        #pragma unroll
        for (int mt=0; mt<MT; ++mt){
          short8 af = *(const short8*)&w_s[(mt*16 + nn)*STR + kt*32 + q*8];
          acc[mt] = __builtin_amdgcn_mfma_f32_16x16x32_bf16(af, bfr[kt], acc[mt], 0, 0, 0);
        }
      }
      __syncthreads();                  // all waves' h1 reads consumed
      if (tid == 0) post1(fsl(fFg, t)); // release h1[t] slot
      #pragma unroll
      for (int mt=0; mt<MT; ++mt){
        #pragma unroll
        for (int r=0;r<4;r++){
          int o = mt*16 + q*4 + r;
          if (o < OUT_D) out[((size_t)t*BB + b)*OUT_D + o] = sigf(acc[mt][r]);
        }
      }
      continue;
    }

    // ---- LSTM pointwise + h publish (roles 0/1) ----
    #pragma unroll
    for (int mt=0; mt<MT; ++mt){
      float ii = sigf(acc[mt][0]);
      float ff = sigf(acc[mt][1]);
      float gg = tanhf2(acc[mt][2]);
      float oo = sigf(acc[mt][3]);
      c[mt] = ff*c[mt] + ii*gg;
      float h = oo * tanhf2(c[mt]);
      hl[mt] = h;
      hT[b*16 + mt*4 + q] = f2bf(h);             // LDS transpose tile [b][unit_local]
    }
    __syncthreads();
    {                                            // coalesced coherent store of h slice
      int bb = tid >> 2, ch = tid & 3;
      if (j0 + ch*4 < HID){
        unsigned long long v = *(const unsigned long long*)&hT[bb*16 + ch*4];
        int kt = j0 >> 5, off = j0 & 31;         // 16 units land inside one kt block
        unsigned short* dst = (ROLE==0 ? h0buf : h1buf)
                            + (size_t)(t&(RING-1))*(BB*KH)
                            + ((size_t)kt*BB + bb)*32 + off + ch*4;
        __hip_atomic_store((unsigned long long*)dst, v,
                           __ATOMIC_RELAXED, __HIP_MEMORY_SCOPE_AGENT);
      }
    }
    asm volatile("s_waitcnt vmcnt(0)" ::: "memory");   // h stores at coherence point
    __syncthreads();
    if (tid == 0){
      if (ROLE == 0){ post1(fsl(f0p, t)); post1(fsl(f0c, t)); }
      else          { post1(fsl(f1p, t)); post1(fsl(f1c, t)); }  // f1g posted early
    }
    if (ROLE == 0) cvt_x(pa, pb, q, xf);               // convert prefetched x for t+1
  }

  if (ROLE < 2){                                   // final hn / cn (fp32)
    size_t base = (size_t)TS*BB*OUT_D;
    float* hn = out + base + (size_t)ROLE*(BB*HID);
    float* cn = out + base + 2*(size_t)BB*HID + (size_t)ROLE*(BB*HID);
    #pragma unroll
    for (int mt=0; mt<MT; ++mt){
      int unit = j0 + mt*4 + q;
      if (unit < HID){
        hn[b*HID + unit] = hl[mt];
        cn[b*HID + unit] = c[mt];
      }
    }
  }
}

__global__ __launch_bounds__(512, 2) void lstm_net(
    const float* __restrict__ x,
    const float* __restrict__ wih0, const float* __restrict__ whh0,
    const float* __restrict__ bih0, const float* __restrict__ bhh0,
    const float* __restrict__ wih1, const float* __restrict__ whh1,
    const float* __restrict__ bih1, const float* __restrict__ bhh1,
    const float* __restrict__ wfc,  const float* __restrict__ bfc,
    float* __restrict__ out,
    unsigned short* h0buf, unsigned short* h1buf,
    unsigned* f0p, unsigned* f0c, unsigned* f1p, unsigned* f1c,
    unsigned* f1g, unsigned* fFg)
{
  __shared__ short w_s[64*456];          // 58368 B (max over roles)
  __shared__ float bias_s[96];
  __shared__ unsigned short hT[128*16];  // h transpose tile
  int wg = blockIdx.x;
  if (wg < NW0){
    run_role<0>(wg*16, x, wih0, whh0, bih0, bhh0, out, h0buf, h1buf,
                f0p, f0c, f1p, f1c, f1g, fFg, w_s, bias_s, hT);
  } else if (wg < NW0+NW1){
    run_role<1>((wg-NW0)*16, x, wih1, whh1, bih1, bhh1, out, h0buf, h1buf,
                f0p, f0c, f1p, f1c, f1g, fFg, w_s, bias_s, hT);
  } else {
    run_role<2>(0, x, wfc, nullptr, bfc, nullptr, out, h0buf, h1buf,
                f0p, f0c, f1p, f1c, f1g, fFg, w_s, bias_s, hT);
  }
}

extern "C" void kernel_launch(void* const* d_in, const int* in_sizes, int n_in,
                              void* d_out, int out_size, void* d_ws, size_t ws_size,
                              hipStream_t stream) {
  const float* x    = (const float*)d_in[0];
  const float* wih0 = (const float*)d_in[1];
  const float* whh0 = (const float*)d_in[2];
  const float* bih0 = (const float*)d_in[3];
  const float* bhh0 = (const float*)d_in[4];
  const float* wih1 = (const float*)d_in[5];
  const float* whh1 = (const float*)d_in[6];
  const float* bih1 = (const float*)d_in[7];
  const float* bhh1 = (const float*)d_in[8];
  const float* wfc  = (const float*)d_in[9];
  const float* bfc  = (const float*)d_in[10];
  float* out = (float*)d_out;

  char* ws = (char*)d_ws;
  const size_t HSZ = (size_t)RING * BB * KH * 2;       // 229376 B per layer ring
  const size_t FSZ = (size_t)FR * FSTR * 4;            // 2048 B per flag array
  unsigned short* h0 = (unsigned short*)(ws + 0);
  unsigned short* h1 = (unsigned short*)(ws + HSZ);
  unsigned* f0p = (unsigned*)(ws + 2*HSZ + 0*FSZ);
  unsigned* f0c = (unsigned*)(ws + 2*HSZ + 1*FSZ);
  unsigned* f1p = (unsigned*)(ws + 2*HSZ + 2*FSZ);
  unsigned* f1c = (unsigned*)(ws + 2*HSZ + 3*FSZ);
  unsigned* f1g = (unsigned*)(ws + 2*HSZ + 4*FSZ);
  unsigned* fFg = (unsigned*)(ws + 2*HSZ + 5*FSZ);

  hipMemsetAsync(d_ws, 0, 2*HSZ + 6*FSZ, stream);      // zero h rings + flags
  hipLaunchKernelGGL(lstm_net, dim3(NWORK), dim3(512), 0, stream,
      x, wih0, whh0, bih0, bhh0, wih1, whh1, bih1, bhh1, wfc, bfc,
      out, h0, h1, f0p, f0c, f1p, f1c, f1g, fFg);
}